// Round 7
// baseline (642.731 us; speedup 1.0000x reference)
//
#include <hip/hip_runtime.h>

typedef __attribute__((ext_vector_type(8))) short short8;
typedef __attribute__((ext_vector_type(4))) float f32x4;
typedef __attribute__((ext_vector_type(4))) int i32x4;

#define NPIX 65536
#define KPITCH 264
#define RED_KSUM 0
#define RED_VSUM 512
#define RED_AGG 1024

__device__ __forceinline__ float b2f(unsigned short u) {
  union { unsigned int i; float f; } z; z.i = ((unsigned int)u) << 16; return z.f;
}
__device__ __forceinline__ unsigned short f2b(float f) {
  union { float f; unsigned int i; } z; z.f = f;
  unsigned int r = z.i + 0x7fffu + ((z.i >> 16) & 1u);
  return (unsigned short)(r >> 16);
}
__device__ __forceinline__ unsigned int packbf(float a, float b) {
  return (unsigned int)f2b(a) | ((unsigned int)f2b(b) << 16);
}
// packed f32->bf16 (RNE), 1 instr per 2 values
__device__ __forceinline__ int cvtpk(float a, float b) {
  int r;
  asm("v_cvt_pk_bf16_f32 %0, %1, %2" : "=v"(r) : "v"(a), "v"(b));
  return r;
}

// Build MFMA A-fragment weights (bf16):
//  - wA[conv][tap][kb][mt][lane][j] = W[o=mt*16+(lane&15)][c=kb*32+(lane>>4)*8+j][tap]
//  - wQKV[pj][kb][mt][lane][j]      = Wp[o=mt*16+(lane&15)][c=kb*32+(lane>>4)*8+j]
// Also zero the reduction region (ws is 0xAA-poisoned before every call).
__global__ __launch_bounds__(256) void prep_kernel(
    const float* __restrict__ W1, const float* __restrict__ W2,
    const float* __restrict__ Wq, const float* __restrict__ Wk,
    const float* __restrict__ Wv,
    unsigned short* __restrict__ wA, unsigned short* __restrict__ wQKV,
    float* __restrict__ red)
{
  const int i = blockIdx.x * 256 + threadIdx.x;
  if (i < 73728) {
    const float* W = (i < 36864) ? W1 : W2;
    const int e = (i < 36864) ? i : (i - 36864);
    const int j    = e & 7;
    const int lane = (e >> 3) & 63;
    const int mt   = (e >> 9) & 3;
    const int kb   = (e >> 11) & 1;
    const int tap  = e >> 12;                 // 0..8 = dy*3+dx
    const int o = mt * 16 + (lane & 15);
    const int c = kb * 32 + ((lane >> 4) << 3) + j;
    wA[i] = f2b(W[o * 576 + c * 9 + tap]);
  } else if (i < 86016) {
    const int e = i - 73728;                  // [pj][kb][mt][lane][j]
    const int j    = e & 7;
    const int lane = (e >> 3) & 63;
    const int mt   = (e >> 9) & 3;
    const int kb   = (e >> 11) & 1;
    const int pj   = e >> 12;                 // 0..2
    const float* W = (pj == 0) ? Wq : (pj == 1) ? Wk : Wv;
    const int o = mt * 16 + (lane & 15);
    const int c = kb * 32 + ((lane >> 4) << 3) + j;
    wQKV[e] = f2b(W[o * 64 + c]);
  } else if (i < 119808) {
    red[i - 86016] = 0.0f;
  }
}

// Pass 1: Q/K/V via 16x16x32 bf16 MFMA, 256-px rounds, 64-px wave tiles.
// Q: L2-normalized, wave-private LDS transpose, dense NHWC bf16 store (ws).
// K/V staged bf16 [64ch][KPITCH px] LDS; agg_kv = Kn.V^T via MFMA over
// k = pixels. Weight A-fragments pre-built in wQKV (prep).
#define PROJ(PIDX, BM)                                                         \
    {                                                                          \
      _Pragma("unroll")                                                        \
      for (int mt = 0; mt < 4; ++mt) {                                         \
        const f32x4 bb = *(const f32x4*)((BM) + mt * 16 + g * 4);              \
        _Pragma("unroll")                                                      \
        for (int nt = 0; nt < 4; ++nt) acc[mt][nt] = bb;                       \
      }                                                                        \
      _Pragma("unroll")                                                        \
      for (int kb = 0; kb < 2; ++kb) {                                         \
        const unsigned short* wp = wQKV + ((PIDX) * 2 + kb) * 2048 + l * 8;    \
        short8 af[4];                                                          \
        _Pragma("unroll")                                                      \
        for (int mt = 0; mt < 4; ++mt)                                         \
          af[mt] = *(const short8*)(wp + mt * 512);                            \
        _Pragma("unroll")                                                      \
        for (int mt = 0; mt < 4; ++mt)                                         \
          _Pragma("unroll")                                                    \
          for (int nt = 0; nt < 4; ++nt)                                       \
            acc[mt][nt] = __builtin_amdgcn_mfma_f32_16x16x32_bf16(             \
                af[mt], bf[nt][kb], acc[mt][nt], 0, 0, 0);                     \
      }                                                                        \
    }

__global__ __launch_bounds__(256, 2) void qkv_kernel(
    const float* __restrict__ x,
    const unsigned short* __restrict__ wQKV,
    const float* __restrict__ bq, const float* __restrict__ bk,
    const float* __restrict__ bv,
    unsigned short* __restrict__ Qn, float* __restrict__ red)
{
  __shared__ __align__(16) unsigned short sh[2 * 64 * KPITCH];
  unsigned short* ks = sh;
  unsigned short* vs = sh + 64 * KPITCH;
  unsigned int* shu = (unsigned int*)sh;
  const int b = blockIdx.y;
  const int t = threadIdx.x;
  const int w = t >> 6;
  const int l = t & 63;
  const int g = l >> 4;
  const int l15 = l & 15;
  const size_t xb = (size_t)b * 64 * NPIX;

  const f32x4 zero = {0.f, 0.f, 0.f, 0.f};
  f32x4 agg[4]  = {zero, zero, zero, zero};
  f32x4 kacc[4] = {zero, zero, zero, zero};
  f32x4 vacc[4] = {zero, zero, zero, zero};

  for (int it = 0; it < 4; ++it) {
    const int pxw = (blockIdx.x << 10) + (it << 8) + (w << 6);  // wave px base

    // ---- x B-fragments (c-contiguous per lane), shared across Q,K,V ----
    short8 bf[4][2];
#pragma unroll
    for (int nt = 0; nt < 4; ++nt) {
      const float* xp = x + xb + (size_t)(g * 8) * NPIX + pxw + nt * 16 + l15;
#pragma unroll
      for (int kb = 0; kb < 2; ++kb) {
        float f[8];
#pragma unroll
        for (int j = 0; j < 8; ++j)
          f[j] = xp[(size_t)(kb * 32 + j) * NPIX];
        union { i32x4 i; short8 s; } u;
        u.i.x = cvtpk(f[0], f[1]); u.i.y = cvtpk(f[2], f[3]);
        u.i.z = cvtpk(f[4], f[5]); u.i.w = cvtpk(f[6], f[7]);
        bf[nt][kb] = u.s;
      }
    }

    f32x4 acc[4][4];

    // ---- Q: project, L2-normalize, LDS transpose, dense NHWC store ----
    PROJ(0, bq);
    {
      float rq[4];
#pragma unroll
      for (int nt = 0; nt < 4; ++nt) {
        float ss = 0.f;
#pragma unroll
        for (int mt = 0; mt < 4; ++mt)
#pragma unroll
          for (int r = 0; r < 4; ++r)
            ss = fmaf(acc[mt][nt][r], acc[mt][nt][r], ss);
        ss += __shfl_xor(ss, 16);
        ss += __shfl_xor(ss, 32);
        rq[nt] = rsqrtf(ss);
      }
      // wave-private transpose region (pitch 72 shorts = 36 uints per px)
      unsigned int* sw = shu + w * 2304;
#pragma unroll
      for (int mt = 0; mt < 4; ++mt)
#pragma unroll
        for (int nt = 0; nt < 4; ++nt) {
          const int px = nt * 16 + l15;
          unsigned int* dst = sw + px * 36 + mt * 8 + g * 2;
          dst[0] = (unsigned)cvtpk(acc[mt][nt][0] * rq[nt], acc[mt][nt][1] * rq[nt]);
          dst[1] = (unsigned)cvtpk(acc[mt][nt][2] * rq[nt], acc[mt][nt][3] * rq[nt]);
        }
      const uint4* rr4 = (const uint4*)(shu + w * 2304);   // 9 uint4 per px
#pragma unroll
      for (int k8 = 0; k8 < 8; ++k8) {
        const int p = (k8 << 3) + (l >> 3);
        const int ch8 = l & 7;
        *(uint4*)(Qn + ((size_t)b * NPIX + pxw + p) * 64 + ch8 * 8) =
            rr4[p * 9 + ch8];
      }
      __syncthreads();   // scratch overlaps ks/vs staging regions
    }

    // ---- K: project, normalize, accumulate ksum, stage to LDS ----
    PROJ(1, bk);
    {
      float rk[4];
#pragma unroll
      for (int nt = 0; nt < 4; ++nt) {
        float ss = 0.f;
#pragma unroll
        for (int mt = 0; mt < 4; ++mt)
#pragma unroll
          for (int r = 0; r < 4; ++r)
            ss = fmaf(acc[mt][nt][r], acc[mt][nt][r], ss);
        ss += __shfl_xor(ss, 16);
        ss += __shfl_xor(ss, 32);
        rk[nt] = rsqrtf(ss);
      }
#pragma unroll
      for (int mt = 0; mt < 4; ++mt)
#pragma unroll
        for (int nt = 0; nt < 4; ++nt)
#pragma unroll
          for (int r = 0; r < 4; ++r) {
            const float kn = acc[mt][nt][r] * rk[nt];
            kacc[mt][r] += kn;
            ks[(mt * 16 + g * 4 + r) * KPITCH + (w << 6) + nt * 16 + l15] =
                (unsigned short)cvtpk(kn, 0.f);
          }
    }

    // ---- V: project, accumulate vsum, stage to LDS ----
    PROJ(2, bv);
    {
#pragma unroll
      for (int mt = 0; mt < 4; ++mt)
#pragma unroll
        for (int nt = 0; nt < 4; ++nt)
#pragma unroll
          for (int r = 0; r < 4; ++r) {
            const float vv = acc[mt][nt][r];
            vacc[mt][r] += vv;
            vs[(mt * 16 + g * 4 + r) * KPITCH + (w << 6) + nt * 16 + l15] =
                (unsigned short)cvtpk(vv, 0.f);
          }
    }
    __syncthreads();

    // ---- agg_kv: MFMA over k = pixels (256 px this iter, 8 k-steps) ----
#pragma unroll
    for (int s = 0; s < 8; ++s) {
      const short8 ak =
          *(const short8*)(ks + (w * 16 + l15) * KPITCH + s * 32 + g * 8);
#pragma unroll
      for (int nt = 0; nt < 4; ++nt) {
        const short8 bv8 =
            *(const short8*)(vs + (nt * 16 + l15) * KPITCH + s * 32 + g * 8);
        agg[nt] = __builtin_amdgcn_mfma_f32_16x16x32_bf16(ak, bv8, agg[nt], 0, 0, 0);
      }
    }
    __syncthreads();
  }

  // ---- reductions: ksum/vsum butterfly over l&15, then global atomics ----
#pragma unroll
  for (int mt = 0; mt < 4; ++mt)
#pragma unroll
    for (int r = 0; r < 4; ++r) {
      float kv = kacc[mt][r], vv = vacc[mt][r];
#pragma unroll
      for (int d = 1; d < 16; d <<= 1) {
        kv += __shfl_xor(kv, d);
        vv += __shfl_xor(vv, d);
      }
      if (l15 == 0) {
        atomicAdd(red + RED_KSUM + b * 64 + mt * 16 + g * 4 + r, kv);
        atomicAdd(red + RED_VSUM + b * 64 + mt * 16 + g * 4 + r, vv);
      }
    }
  float* ab = red + RED_AGG + b * 4096;
#pragma unroll
  for (int nt = 0; nt < 4; ++nt)
#pragma unroll
    for (int r = 0; r < 4; ++r)
      atomicAdd(ab + (w * 16 + g * 4 + r) * 64 + nt * 16 + l15, agg[nt][r]);
}

// Prep2 (alias-safe, one block per batch): copies agg/ksum/vsum to LDS,
// then writes Cb (bf16 hi+residual A-frags), u = Wr.vsum, ks2 = ksum+eps
// IN PLACE over the red region (outputs overlay the copied inputs).
__global__ __launch_bounds__(256) void prep2_kernel(
    const float* __restrict__ Wr, const float* __restrict__ red,
    unsigned short* __restrict__ Cb, float* __restrict__ u,
    float* __restrict__ ks2)
{
  __shared__ float sagg[4096];
  __shared__ float skv[128];
  const int b = blockIdx.x;
  const int t = threadIdx.x;
  const float* aggg = red + RED_AGG + b * 4096;
  for (int i = t; i < 4096; i += 256) sagg[i] = aggg[i];
  if (t < 64) skv[t] = red[RED_KSUM + b * 64 + t];
  else if (t < 128) skv[t] = red[RED_VSUM + b * 64 + (t - 64)];
  __syncthreads();
  const int o = t & 63;
  const int kq = t >> 6;                 // 0..3
  const float* wr = Wr + o * 64;
  for (int i = 0; i < 16; ++i) {
    const int k = kq * 16 + i;
    const float* ar = sagg + k * 64;
    float s = 0.f;
#pragma unroll
    for (int v = 0; v < 64; ++v) s = fmaf(wr[v], ar[v], s);
    const int mt = o >> 4, kb = k >> 5;
    const int lane = (o & 15) | (((k >> 3) & 3) << 4);
    const int j = k & 7;
    const unsigned short c1 = f2b(s);
    const float r1 = s - b2f(c1);
    Cb[b * 4096 + ((kb * 4 + mt) * 64 + lane) * 8 + j] = c1;
    Cb[32768 + b * 4096 + ((kb * 4 + mt) * 64 + lane) * 8 + j] = f2b(r1);
  }
  if (t < 64) {
    float s = 0.f;
#pragma unroll
    for (int v = 0; v < 64; ++v) s = fmaf(Wr[t * 64 + v], skv[64 + v], s);
    u[b * 64 + t] = s;
    ks2[b * 64 + t] = skv[t] + 1e-6f;
  }
}

// MEGA: inline attn + double 3x3 SAME conv (64->64->64) + residual.
// Per block: 8x32 out. Phase A (waves 0..6): compute attn for the 12x36
// in-tile (432 px) from Qn -- denom via shfl_xor, C-MFMA (C1+C2 bf16
// split), *denom+br -- written transposed straight into LDS (NHWC bf16,
// zeros outside image = conv1 SAME pad). Phase B (waves 0..5): conv1 from
// LDS -> acc; barrier; overwrite same LDS with the 10x34 mid tile (zeros
// at image border = conv2 SAME pad). Phase C (8 waves): conv2 + fused
// *x+x fp32 NCHW epilogue. 62KB LDS -> 2 blocks/CU of 512 thr.
__global__ __launch_bounds__(512, 4) void mega_kernel(
    const unsigned short* __restrict__ Qn,   // NHWC bf16 (ws)
    const unsigned short* __restrict__ Cb,   // C1||C2 A-frags
    const float* __restrict__ u,
    const float* __restrict__ ks2,
    const float* __restrict__ br,
    const unsigned short* __restrict__ wA,   // wA1 | wA2 at +36864 shorts
    const float* __restrict__ b1, const float* __restrict__ b2,
    const float* __restrict__ xin,           // NCHW fp32
    float* __restrict__ outf)                // NCHW fp32
{
  __shared__ __align__(16) unsigned short lds[432 * 72];   // 62208 B
  const int bz = blockIdx.z;
  const int ty0 = blockIdx.y << 3;
  const int tx0 = blockIdx.x << 5;
  const int tid = threadIdx.x;
  const int w = tid >> 6, lane = tid & 63, q = lane >> 4, l = lane & 15;
  const size_t nb = (size_t)bz * NPIX;
  unsigned int* mu = (unsigned int*)lds;

  // ---- phase A: attn for in-tile px (iy 0..11, ix 0..35), waves 0..6 ----
  if (w < 7) {
    float ksl[16];
#pragma unroll
    for (int kb = 0; kb < 2; ++kb)
#pragma unroll
      for (int j = 0; j < 8; ++j)
        ksl[kb * 8 + j] = ks2[bz * 64 + kb * 32 + q * 8 + j];
    f32x4 brf[4];
#pragma unroll
    for (int mt = 0; mt < 4; ++mt)
      brf[mt] = *(const f32x4*)(br + mt * 16 + q * 4);

#pragma unroll
    for (int nt = 0; nt < 4; ++nt) {
      const int mp = w * 64 + nt * 16 + l;     // in-tile px (may be >=432)
      const int iy = mp / 36;
      const int ix = mp - iy * 36;
      const int gy = ty0 + iy - 2;
      const int gx = tx0 + ix - 2;
      const bool okimg = ((unsigned)gy < 256u) && ((unsigned)gx < 256u);
      short8 qf0 = {0, 0, 0, 0, 0, 0, 0, 0};
      short8 qf1 = {0, 0, 0, 0, 0, 0, 0, 0};
      if (okimg && mp < 432) {
        const unsigned short* qp = Qn + ((nb + (gy << 8) + gx) << 6) + (q << 3);
        qf0 = *(const short8*)qp;
        qf1 = *(const short8*)(qp + 32);
      }
      float ss = 0.f;
#pragma unroll
      for (int j = 0; j < 8; ++j)
        ss = fmaf(b2f((unsigned short)qf0[j]), ksl[j], ss);
#pragma unroll
      for (int j = 0; j < 8; ++j)
        ss = fmaf(b2f((unsigned short)qf1[j]), ksl[8 + j], ss);
      ss += __shfl_xor(ss, 16);
      ss += __shfl_xor(ss, 32);
      const float denom = 1.0f / (65536.0f + ss);
      f32x4 acc[4];
#pragma unroll
      for (int mt = 0; mt < 4; ++mt)
        acc[mt] = *(const f32x4*)(u + bz * 64 + mt * 16 + q * 4);
#pragma unroll
      for (int lvl = 0; lvl < 2; ++lvl)
#pragma unroll
        for (int kb = 0; kb < 2; ++kb) {
          const unsigned short* cp =
              Cb + lvl * 32768 + bz * 4096 + ((kb * 4) * 64 + lane) * 8;
          const short8 qv = kb ? qf1 : qf0;
#pragma unroll
          for (int mt = 0; mt < 4; ++mt) {
            const short8 af = *(const short8*)(cp + mt * 512);
            acc[mt] = __builtin_amdgcn_mfma_f32_16x16x32_bf16(
                af, qv, acc[mt], 0, 0, 0);
          }
        }
      if (mp < 432) {
        unsigned int* dst = mu + mp * 36 + q * 2;
#pragma unroll
        for (int mt = 0; mt < 4; ++mt) {
          const unsigned a0 = okimg
              ? (unsigned)cvtpk(fmaf(acc[mt][0], denom, brf[mt][0]),
                                fmaf(acc[mt][1], denom, brf[mt][1])) : 0u;
          const unsigned a1 = okimg
              ? (unsigned)cvtpk(fmaf(acc[mt][2], denom, brf[mt][2]),
                                fmaf(acc[mt][3], denom, brf[mt][3])) : 0u;
          dst[mt * 8] = a0;
          dst[mt * 8 + 1] = a1;
        }
      }
    }
  }
  __syncthreads();

  // ---- phase B: conv1 from LDS in-tile; waves 0..5 own 340 mid px ----
  f32x4 acc1[4][4];
  int ylv[4], xlv[4];
  if (w < 6) {
#pragma unroll
    for (int mt = 0; mt < 4; ++mt) {
      const f32x4 bb = *(const f32x4*)(b1 + mt * 16 + q * 4);
#pragma unroll
      for (int nt = 0; nt < 4; ++nt) acc1[mt][nt] = bb;
    }
#pragma unroll
    for (int nt = 0; nt < 4; ++nt) {
      const int mp = w * 64 + nt * 16 + l;
      const int mpc = mp < 340 ? mp : 339;
      ylv[nt] = mpc / 34;                 // mid row 0..9
      xlv[nt] = mpc - ylv[nt] * 34;       // mid col 0..33
    }
    const short8* tpIn = (const short8*)lds;   // 9 short8 per in-tile px
    for (int tap = 0; tap < 9; ++tap) {
      const int dy = tap / 3, dx = tap - dy * 3;
#pragma unroll
      for (int kb = 0; kb < 2; ++kb) {
        const unsigned short* wp = wA + (tap * 2 + kb) * 2048 + lane * 8;
        short8 af[4];
#pragma unroll
        for (int mt = 0; mt < 4; ++mt) af[mt] = *(const short8*)(wp + mt * 512);
        short8 bfv[4];
#pragma unroll
        for (int nt = 0; nt < 4; ++nt)
          bfv[nt] = tpIn[((ylv[nt] + dy) * 36 + (xlv[nt] + dx)) * 9 +
                         (kb << 2) + q];
#pragma unroll
        for (int mt = 0; mt < 4; ++mt)
#pragma unroll
          for (int nt = 0; nt < 4; ++nt)
            acc1[mt][nt] = __builtin_amdgcn_mfma_f32_16x16x32_bf16(
                af[mt], bfv[nt], acc1[mt][nt], 0, 0, 0);
      }
    }
  }
  __syncthreads();   // all conv1 LDS reads done before mid overwrites

  if (w < 6) {
    // ---- mid NHWC bf16 write (same LDS); zero outside image ----
#pragma unroll
    for (int nt = 0; nt < 4; ++nt) {
      const int mp = w * 64 + nt * 16 + l;
      if (mp < 340) {
        const int gym = ty0 + ylv[nt] - 1;
        const int gxm = tx0 + xlv[nt] - 1;
        const bool ok = ((unsigned)gym < 256u) && ((unsigned)gxm < 256u);
#pragma unroll
        for (int mt = 0; mt < 4; ++mt) {
          unsigned int* dst = mu + mp * 36 + mt * 8 + q * 2;
          dst[0] = ok ? packbf(acc1[mt][nt][0], acc1[mt][nt][1]) : 0u;
          dst[1] = ok ? packbf(acc1[mt][nt][2], acc1[mt][nt][3]) : 0u;
        }
      }
    }
  }
  __syncthreads();

  // ---- phase C: conv2 (wave w -> out row ty0+w, 32 cols) + *x+x ----
  f32x4 acc2[4][2];
#pragma unroll
  for (int mt = 0; mt < 4; ++mt) {
    const f32x4 bb = *(const f32x4*)(b2 + mt * 16 + q * 4);
    acc2[mt][0] = bb; acc2[mt][1] = bb;
  }
  const short8* tp2 = (const short8*)lds;   // 9 short8 per mid pixel
  const unsigned short* wA2p = wA + 36864;
  for (int tap = 0; tap < 9; ++tap) {
    const int dy = tap / 3, dx = tap - dy * 3;
#pragma unroll
    for (int kb = 0; kb < 2; ++kb) {
      const unsigned short* wp = wA2p + (tap * 2 + kb) * 2048 + lane * 8;
      short8 af[4];
#pragma unroll
      for (int mt = 0; mt < 4; ++mt) af[mt] = *(const short8*)(wp + mt * 512);
      short8 bf2[2];
#pragma unroll
      for (int nt = 0; nt < 2; ++nt) {
        const int yl = w + dy;                    // 0..9
        const int xl = nt * 16 + l + dx;          // 0..33
        bf2[nt] = tp2[(yl * 34 + xl) * 9 + (kb << 2) + q];
      }
#pragma unroll
      for (int mt = 0; mt < 4; ++mt)
#pragma unroll
        for (int nt = 0; nt < 2; ++nt)
          acc2[mt][nt] = __builtin_amdgcn_mfma_f32_16x16x32_bf16(
              af[mt], bf2[nt], acc2[mt][nt], 0, 0, 0);
    }
  }
#pragma unroll
  for (int mt = 0; mt < 4; ++mt)
#pragma unroll
    for (int nt = 0; nt < 2; ++nt) {
      const int gx = tx0 + nt * 16 + l;
      const int gy = ty0 + w;
#pragma unroll
      for (int r = 0; r < 4; ++r) {
        const int o = (mt << 4) + (q << 2) + r;
        const size_t idx = (((size_t)bz * 64 + o) << 16) + (gy << 8) + gx;
        const float xo = xin[idx];
        outf[idx] = fmaf(acc2[mt][nt][r], xo, xo);
      }
    }
}

extern "C" void kernel_launch(void* const* d_in, const int* in_sizes, int n_in,
                              void* d_out, int out_size, void* d_ws, size_t ws_size,
                              hipStream_t stream) {
  (void)in_sizes; (void)n_in; (void)out_size; (void)ws_size;
  const float* x  = (const float*)d_in[0];
  const float* Wq = (const float*)d_in[1];
  const float* bq = (const float*)d_in[2];
  const float* Wk = (const float*)d_in[3];
  const float* bk = (const float*)d_in[4];
  const float* Wv = (const float*)d_in[5];
  const float* bv = (const float*)d_in[6];
  const float* Wr = (const float*)d_in[7];
  const float* br = (const float*)d_in[8];
  const float* W1 = (const float*)d_in[9];
  const float* b1 = (const float*)d_in[10];
  const float* W2 = (const float*)d_in[11];
  const float* b2 = (const float*)d_in[12];

  // ws layout (peak identical to prior proven 67391488 B):
  //  wA1 [0,73728)  wA2 [73728,147456)            -- live till mega
  //  red [147456,282624) (33792 fp32, exact fit)  -- prep/qkv -> prep2
  //    after prep2, overlaid IN PLACE by:
  //    u [147456,+2048) ks2 [+2048,+4096) Cb [+4096,+135168)  -- -> mega
  //  Qn  [282624,67391488) NHWC bf16              -- qkv -> mega
  // d_out scratch: wQKV at +67108864 (prep -> qkv, dead before mega's
  // full d_out overwrite).
  unsigned short* wA1 = (unsigned short*)d_ws;
  float* red = (float*)((char*)d_ws + 147456);
  float* u_  = (float*)((char*)d_ws + 147456);
  float* ks2 = (float*)((char*)d_ws + 147456 + 2048);
  unsigned short* Cb = (unsigned short*)((char*)d_ws + 147456 + 4096);
  unsigned short* Qn = (unsigned short*)((char*)d_ws + 282624);
  unsigned short* wQKV = (unsigned short*)((char*)d_out + 67108864);

  prep_kernel<<<468, 256, 0, stream>>>(W1, W2, Wq, Wk, Wv, wA1, wQKV, red);
  qkv_kernel<<<dim3(64, 8), 256, 0, stream>>>(x, wQKV, bq, bk, bv, Qn, red);
  prep2_kernel<<<8, 256, 0, stream>>>(Wr, red, Cb, u_, ks2);
  mega_kernel<<<dim3(8, 32, 8), 512, 0, stream>>>(
      Qn, Cb, u_, ks2, br, wA1, b1, b2, x, (float*)d_out);
}